// Round 2
// baseline (20570.930 us; speedup 1.0000x reference)
//
#include <hip/hip_runtime.h>
#include <hip/hip_bf16.h>

// LSTM B=64 S=512 I=H=1024.
// Phase 1: xg[b*S+s][4H] = x @ W_ih^T + (b_ih+b_hh), bf16 MFMA GEMM (M=32768,N=4096,K=1024).
// Phase 2: persistent 256-block kernel; block p owns hidden cols [p*4, p*4+4) for all 4 gates
//          (16 rows of W_hh in LDS for the whole sequence), c-slice in registers,
//          h exchanged via global double buffer + per-step device-scope barrier.

typedef __bf16 bf16x8 __attribute__((ext_vector_type(8)));
typedef float f32x4 __attribute__((ext_vector_type(4)));

__device__ __forceinline__ unsigned short f2b(float f) {
  unsigned u = __builtin_bit_cast(unsigned, f);
  u += 0x7fffu + ((u >> 16) & 1u);           // round-to-nearest-even
  return (unsigned short)(u >> 16);
}
__device__ __forceinline__ float b2f(unsigned short s) {
  return __builtin_bit_cast(float, (unsigned)s << 16);
}
__device__ __forceinline__ float sigmoidf_(float z) { return 1.f / (1.f + __expf(-z)); }
__device__ __forceinline__ float tanh_fast(float z) {
  z = fminf(15.f, fmaxf(-15.f, z));
  float e2 = __expf(2.f * z);
  return (e2 - 1.f) / (e2 + 1.f);
}

// global -> LDS async 16B (CK-style address-space casts)
__device__ __forceinline__ void g2l16(const unsigned short* gp, unsigned short* lp) {
  auto g1 = reinterpret_cast<__attribute__((address_space(1))) unsigned short*>(
      reinterpret_cast<unsigned long long>(gp));
  auto l3 = reinterpret_cast<__attribute__((address_space(3))) unsigned short*>(
      reinterpret_cast<unsigned long long>(lp));
  __builtin_amdgcn_global_load_lds(g1, l3, 16, 0, 0);
}

__global__ __launch_bounds__(256) void cvt_bf16_k(const float* __restrict__ src,
                                                  unsigned short* __restrict__ dst, int n4) {
  int i = blockIdx.x * 256 + threadIdx.x;
  if (i >= n4) return;
  float4 v = reinterpret_cast<const float4*>(src)[i];
  ushort4 o;
  o.x = f2b(v.x); o.y = f2b(v.y); o.z = f2b(v.z); o.w = f2b(v.w);
  reinterpret_cast<ushort4*>(dst)[i] = o;
}

__global__ __launch_bounds__(256) void bias_k(const float* __restrict__ a,
                                              const float* __restrict__ b,
                                              float* __restrict__ o) {
  int i = blockIdx.x * 256 + threadIdx.x;
  if (i < 4096) o[i] = a[i] + b[i];
}

// xg GEMM: A = x (fp32, cvt->bf16 via regs), B = W_ih bf16 (global_load_lds), NT, 128x128x32 tiles
__global__ __launch_bounds__(256) void gemm_xg_k(const float* __restrict__ X,
                                                 const unsigned short* __restrict__ Wb,
                                                 const float* __restrict__ bias,
                                                 unsigned short* __restrict__ xg) {
  __shared__ __align__(16) unsigned short As[128 * 32];
  __shared__ __align__(16) unsigned short Bs[128 * 32];
  const int tid = threadIdx.x;
  const int w = tid >> 6, l = tid & 63;
  const int rowBase = blockIdx.y * 128;   // M (= b*S+s)
  const int colBase = blockIdx.x * 128;   // N (= gate dim)
  const int wm = w & 1, wn = w >> 1;
  f32x4 acc[4][4] = {};

  for (int kt = 0; kt < 32; ++kt) {
    __syncthreads();
    const int k0 = kt * 32;
    // B tile: 8 chunks of 1KB; chunk c = p*4+w; lane l -> row c*16+l/4, k (l&3)*8
#pragma unroll
    for (int p = 0; p < 2; ++p) {
      int c = p * 4 + w;
      const unsigned short* gp = Wb + (colBase + c * 16 + (l >> 2)) * 1024 + k0 + (l & 3) * 8;
      g2l16(gp, &Bs[c * 512]);
    }
    // A tile: fp32 load + cvt to bf16
#pragma unroll
    for (int i = 0; i < 4; ++i) {
      int idx = tid + i * 256;          // 0..1023 chunks of 4 floats
      int r = idx >> 3;
      int cc = (idx & 7) * 4;
      const float4 v = *reinterpret_cast<const float4*>(X + (long)(rowBase + r) * 1024 + k0 + cc);
      uint2 u;
      u.x = ((unsigned)f2b(v.y) << 16) | (unsigned)f2b(v.x);
      u.y = ((unsigned)f2b(v.w) << 16) | (unsigned)f2b(v.z);
      *reinterpret_cast<uint2*>(&As[r * 32 + cc]) = u;
    }
    __syncthreads();
    bf16x8 af[4], bfr[4];
#pragma unroll
    for (int mt = 0; mt < 4; ++mt)
      af[mt] = *reinterpret_cast<const bf16x8*>(&As[(wm * 64 + mt * 16 + (l & 15)) * 32 + (l >> 4) * 8]);
#pragma unroll
    for (int nt = 0; nt < 4; ++nt)
      bfr[nt] = *reinterpret_cast<const bf16x8*>(&Bs[(wn * 64 + nt * 16 + (l & 15)) * 32 + (l >> 4) * 8]);
#pragma unroll
    for (int mt = 0; mt < 4; ++mt)
#pragma unroll
      for (int nt = 0; nt < 4; ++nt)
        acc[mt][nt] = __builtin_amdgcn_mfma_f32_16x16x32_bf16(af[mt], bfr[nt], acc[mt][nt], 0, 0, 0);
  }
  // epilogue: +bias, cvt, store bf16. D layout: row m=(l>>4)*4+r, col n=l&15 (guide-verified)
#pragma unroll
  for (int nt = 0; nt < 4; ++nt) {
    int n = colBase + wn * 64 + nt * 16 + (l & 15);
    float bv = bias[n];
#pragma unroll
    for (int mt = 0; mt < 4; ++mt) {
      int m0 = rowBase + wm * 64 + mt * 16 + (l >> 4) * 4;
#pragma unroll
      for (int r = 0; r < 4; ++r)
        xg[(long)(m0 + r) * 4096 + n] = f2b(acc[mt][nt][r] + bv);
    }
  }
}

// Persistent recurrence. 256 blocks x 256 threads. Block (logical pl) owns cols [pl*4, pl*4+4).
__global__ __launch_bounds__(256) void lstm_rec_k(const unsigned short* __restrict__ Whb,
                                                  const unsigned short* __restrict__ xg,
                                                  unsigned short* __restrict__ hbuf,
                                                  int* __restrict__ cnt,
                                                  float* __restrict__ out) {
  __shared__ __align__(16) unsigned short Wl[16][1032];  // +8 pad: breaks 16-way LDS bank conflict
  __shared__ float gS[64][17];
  const int tid = threadIdx.x;
  const int w = tid >> 6, l = tid & 63;
  const int nblk = (int)gridDim.x;
  // XCD swizzle: consecutive logical slices land on the same XCD (xg line sharing)
  const int pl = (blockIdx.x & 7) * 32 + (blockIdx.x >> 3);
  const int col0 = pl * 4;

  // Stage W_hh slice: LDS row nl = g*4+jj  <-  W_hh row g*1024 + col0 + jj
  for (int row = w; row < 16; row += 4) {
    int grow = (row >> 2) * 1024 + col0 + (row & 3);
#pragma unroll
    for (int rep = 0; rep < 2; ++rep) {
      int off = l * 8 + rep * 512;
      *reinterpret_cast<uint4*>(&Wl[row][off]) =
          *reinterpret_cast<const uint4*>(Whb + grow * 1024 + off);
    }
  }
  __syncthreads();

  float c = 0.f;
  const int b = tid >> 2, jj = tid & 3;      // epilogue thread owns (batch b, col jj)
  const int arow = w * 16 + (l & 15);        // A-operand batch row
  const int koff = (l >> 4) * 8;
  const int wrow = l & 15;                   // B-operand gate row
  float* Hout = out;
  float* Cout = out + 33554432;              // B*S*H

  for (int t = 0; t < 512; ++t) {
    const unsigned short* hcur = hbuf + (t & 1) * 65536;
    // prefetch xg for this (b,t) early; overlaps MFMA phase
    const unsigned short* xp = xg + (b * 512 + t) * 4096 + col0 + jj;
    unsigned short x0 = xp[0], x1 = xp[1024], x2 = xp[2048], x3 = xp[3072];

    f32x4 acc = {0.f, 0.f, 0.f, 0.f};
#pragma unroll
    for (int kt = 0; kt < 32; ++kt) {
      bf16x8 a  = *reinterpret_cast<const bf16x8*>(hcur + arow * 1024 + kt * 32 + koff);
      bf16x8 bb = *reinterpret_cast<const bf16x8*>(&Wl[wrow][kt * 32 + koff]);
      acc = __builtin_amdgcn_mfma_f32_16x16x32_bf16(a, bb, acc, 0, 0, 0);
    }
#pragma unroll
    for (int r = 0; r < 4; ++r) gS[w * 16 + (l >> 4) * 4 + r][l & 15] = acc[r];
    __syncthreads();

    float zi = gS[b][jj]      + b2f(x0);
    float zf = gS[b][4 + jj]  + b2f(x1);
    float zg = gS[b][8 + jj]  + b2f(x2);
    float zo = gS[b][12 + jj] + b2f(x3);
    float ig = sigmoidf_(zi), fg = sigmoidf_(zf), og = sigmoidf_(zo);
    float gg = tanh_fast(zg);
    c = fg * c + ig * gg;
    float hn = og * tanh_fast(c);
    int oidx = b * (512 * 1024) + t * 1024 + col0 + jj;
    hbuf[((t + 1) & 1) * 65536 + b * 1024 + col0 + jj] = f2b(hn);
    Hout[oidx] = hn;
    Cout[oidx] = c;
    __syncthreads();   // gS WAR + ensure all waves' h stores issued before fence

    if (t < 511) {
      if (tid == 0) {
        __threadfence();                      // flush h slice device-wide
        atomicAdd(&cnt[t], 1);
        while (__hip_atomic_load(&cnt[t], __ATOMIC_RELAXED, __HIP_MEMORY_SCOPE_AGENT) < nblk)
          __builtin_amdgcn_s_sleep(1);
      }
      __syncthreads();
      __threadfence();                        // acquire: invalidate caches before reading fresh h
    }
  }
}

extern "C" void kernel_launch(void* const* d_in, const int* in_sizes, int n_in,
                              void* d_out, int out_size, void* d_ws, size_t ws_size,
                              hipStream_t stream) {
  const float* x    = (const float*)d_in[0];
  const float* W_ih = (const float*)d_in[1];
  const float* W_hh = (const float*)d_in[2];
  const float* b_ih = (const float*)d_in[3];
  const float* b_hh = (const float*)d_in[4];

  char* ws = (char*)d_ws;
  int* cnt             = (int*)ws;                         // 512 ints
  unsigned short* hbuf = (unsigned short*)(ws + 4096);     // 2 x 64x1024 bf16
  float* biasS         = (float*)(ws + 266240);            // 4096 f32
  unsigned short* Wihb = (unsigned short*)(ws + 282624);   // 8 MB bf16
  unsigned short* Whhb = (unsigned short*)(ws + 8671232);  // 8 MB bf16
  unsigned short* xgb  = (unsigned short*)(ws + 17059840); // 268 MB bf16 [32768][4096]
  float* out = (float*)d_out;

  (void)hipMemsetAsync(ws, 0, 266240, stream);             // zero barrier counters + h0
  cvt_bf16_k<<<4096, 256, 0, stream>>>(W_ih, Wihb, 1048576);
  cvt_bf16_k<<<4096, 256, 0, stream>>>(W_hh, Whhb, 1048576);
  bias_k<<<16, 256, 0, stream>>>(b_ih, b_hh, biasS);
  gemm_xg_k<<<dim3(32, 256), 256, 0, stream>>>(x, Wihb, biasS, xgb);
  lstm_rec_k<<<256, 256, 0, stream>>>(Whhb, xgb, hbuf, cnt, out);
}

// Round 3
// 4178.769 us; speedup vs baseline: 4.9227x; 4.9227x over previous
//
#include <hip/hip_runtime.h>
#include <hip/hip_bf16.h>

// LSTM B=64 S=512 I=H=1024.
// Phase 1: xg = x @ W_ih^T + bias (bf16 MFMA GEMM, unchanged from R2 - passed).
// Phase 2: persistent 128-block x 512-thread recurrence. Block owns 8 hidden cols
//          (32 gate-rows). W_hh slab lives in 128 VGPRs/wave. Full h staged to LDS
//          each step via LLC-coherent global_load_lds (aux=SC0|SC1). Cross-block
//          sync: relaxed agent atomics only - NO threadfence/wbl2 anywhere.

#define NBLK 128

typedef __bf16 bf16x8 __attribute__((ext_vector_type(8)));
typedef float f32x4 __attribute__((ext_vector_type(4)));

__device__ __forceinline__ unsigned short f2b(float f) {
  unsigned u = __builtin_bit_cast(unsigned, f);
  u += 0x7fffu + ((u >> 16) & 1u);
  return (unsigned short)(u >> 16);
}
__device__ __forceinline__ float b2f(unsigned short s) {
  return __builtin_bit_cast(float, (unsigned)s << 16);
}
__device__ __forceinline__ float sigmoidf_(float z) { return 1.f / (1.f + __expf(-z)); }
__device__ __forceinline__ float tanh_fast(float z) {
  z = fminf(15.f, fmaxf(-15.f, z));
  float e2 = __expf(2.f * z);
  return (e2 - 1.f) / (e2 + 1.f);
}

template <int AUX>
__device__ __forceinline__ void g2l16(const unsigned short* gp, unsigned short* lp) {
  auto g1 = reinterpret_cast<__attribute__((address_space(1))) unsigned short*>(
      reinterpret_cast<unsigned long long>(gp));
  auto l3 = reinterpret_cast<__attribute__((address_space(3))) unsigned short*>(
      reinterpret_cast<unsigned long long>(lp));
  __builtin_amdgcn_global_load_lds(g1, l3, 16, 0, AUX);
}

__global__ __launch_bounds__(256) void cvt_bf16_k(const float* __restrict__ src,
                                                  unsigned short* __restrict__ dst, int n4) {
  int i = blockIdx.x * 256 + threadIdx.x;
  if (i >= n4) return;
  float4 v = reinterpret_cast<const float4*>(src)[i];
  ushort4 o;
  o.x = f2b(v.x); o.y = f2b(v.y); o.z = f2b(v.z); o.w = f2b(v.w);
  reinterpret_cast<ushort4*>(dst)[i] = o;
}

__global__ __launch_bounds__(256) void bias_k(const float* __restrict__ a,
                                              const float* __restrict__ b,
                                              float* __restrict__ o) {
  int i = blockIdx.x * 256 + threadIdx.x;
  if (i < 4096) o[i] = a[i] + b[i];
}

// xg GEMM (unchanged, correctness-verified in R2)
__global__ __launch_bounds__(256) void gemm_xg_k(const float* __restrict__ X,
                                                 const unsigned short* __restrict__ Wb,
                                                 const float* __restrict__ bias,
                                                 unsigned short* __restrict__ xg) {
  __shared__ __align__(16) unsigned short As[128 * 32];
  __shared__ __align__(16) unsigned short Bs[128 * 32];
  const int tid = threadIdx.x;
  const int w = tid >> 6, l = tid & 63;
  const int rowBase = blockIdx.y * 128;
  const int colBase = blockIdx.x * 128;
  const int wm = w & 1, wn = w >> 1;
  f32x4 acc[4][4] = {};

  for (int kt = 0; kt < 32; ++kt) {
    __syncthreads();
    const int k0 = kt * 32;
#pragma unroll
    for (int p = 0; p < 2; ++p) {
      int c = p * 4 + w;
      const unsigned short* gp = Wb + (colBase + c * 16 + (l >> 2)) * 1024 + k0 + (l & 3) * 8;
      g2l16<0>(gp, &Bs[c * 512]);
    }
#pragma unroll
    for (int i = 0; i < 4; ++i) {
      int idx = tid + i * 256;
      int r = idx >> 3;
      int cc = (idx & 7) * 4;
      const float4 v = *reinterpret_cast<const float4*>(X + (long)(rowBase + r) * 1024 + k0 + cc);
      uint2 u;
      u.x = ((unsigned)f2b(v.y) << 16) | (unsigned)f2b(v.x);
      u.y = ((unsigned)f2b(v.w) << 16) | (unsigned)f2b(v.z);
      *reinterpret_cast<uint2*>(&As[r * 32 + cc]) = u;
    }
    __syncthreads();
    bf16x8 af[4], bfr[4];
#pragma unroll
    for (int mt = 0; mt < 4; ++mt)
      af[mt] = *reinterpret_cast<const bf16x8*>(&As[(wm * 64 + mt * 16 + (l & 15)) * 32 + (l >> 4) * 8]);
#pragma unroll
    for (int nt = 0; nt < 4; ++nt)
      bfr[nt] = *reinterpret_cast<const bf16x8*>(&Bs[(wn * 64 + nt * 16 + (l & 15)) * 32 + (l >> 4) * 8]);
#pragma unroll
    for (int mt = 0; mt < 4; ++mt)
#pragma unroll
      for (int nt = 0; nt < 4; ++nt)
        acc[mt][nt] = __builtin_amdgcn_mfma_f32_16x16x32_bf16(af[mt], bfr[nt], acc[mt][nt], 0, 0, 0);
  }
#pragma unroll
  for (int nt = 0; nt < 4; ++nt) {
    int n = colBase + wn * 64 + nt * 16 + (l & 15);
    float bv = bias[n];
#pragma unroll
    for (int mt = 0; mt < 4; ++mt) {
      int m0 = rowBase + wm * 64 + mt * 16 + (l >> 4) * 4;
#pragma unroll
      for (int r = 0; r < 4; ++r)
        xg[(long)(m0 + r) * 4096 + n] = f2b(acc[mt][nt][r] + bv);
    }
  }
}

// Persistent recurrence: 128 blocks x 512 threads, block owns cols [pl*8, pl*8+8).
__global__ __launch_bounds__(512, 2) void lstm_rec_k(const unsigned short* __restrict__ Whb,
                                                     const unsigned short* __restrict__ xg,
                                                     unsigned short* __restrict__ hbuf,
                                                     int* __restrict__ cnt,
                                                     float* __restrict__ out) {
  // h rows padded +8 shorts: stride 516 dw == 4 mod 32 -> 2-way LDS access (free)
  __shared__ __align__(16) unsigned short hL[64 * 1032];   // 129 KB
  __shared__ float gS[64][36];                             // 9 KB, stride 36 dw == 4 mod 32
  __shared__ __align__(16) unsigned short hS[64][8];       // 2 KB

  const int tid = threadIdx.x;
  const int w = tid >> 6, l = tid & 63;
  // XCD swizzle: adjacent col-slices share an XCD (xg L2 line reuse)
  const int pl = (blockIdx.x & 7) * 16 + (blockIdx.x >> 3);
  const int col0 = pl * 8;

  // W_hh slab -> VGPRs. Wave w: wb=w&3 batch-tile, wn=w>>2 gaterow-tile (0..1).
  // Slab row n = g*8+cc  <->  W_hh global row g*1024 + col0 + cc.
  const int wb = w & 3, wn = w >> 2;
  bf16x8 warr[32];
  {
    int n = wn * 16 + (l & 15);
    int g = n >> 3, cc = n & 7;
    const unsigned short* wp = Whb + (unsigned)(g * 1024 + col0 + cc) * 1024 + (l >> 4) * 8;
#pragma unroll
    for (int kt = 0; kt < 32; ++kt)
      warr[kt] = *reinterpret_cast<const bf16x8*>(wp + kt * 32);
  }

  float c = 0.f;
  const int eb = tid >> 3, ec = tid & 7;   // epilogue: thread owns (batch eb, col ec)
  const int arow = wb * 16 + (l & 15);
  float* Hout = out;
  float* Cout = out + 33554432;

  for (int t = 0; t < 512; ++t) {
    const unsigned short* hcur = hbuf + (t & 1) * 65536;
    // Stage full h (64x1024 bf16) into LDS: 128 x 1KB chunks, LLC-coherent (SC0|SC1)
#pragma unroll
    for (int j = 0; j < 16; ++j) {
      int ch = w * 16 + j;
      int r = ch >> 1, hf = ch & 1;
      g2l16<0x11>(hcur + r * 1024 + hf * 512 + l * 8, &hL[r * 1032 + hf * 512 + l * 8]);
    }
    // xg prefetch for epilogue (normal cached loads; written by prior kernel)
    const unsigned short* xp = xg + ((eb << 9) + t) * 4096 + col0 + ec;
    unsigned short x0 = xp[0], x1 = xp[1024], x2 = xp[2048], x3 = xp[3072];
    asm volatile("s_waitcnt vmcnt(0)" ::: "memory");
    __syncthreads();

    f32x4 acc = {0.f, 0.f, 0.f, 0.f};
#pragma unroll
    for (int kt = 0; kt < 32; ++kt) {
      bf16x8 a = *reinterpret_cast<const bf16x8*>(&hL[arow * 1032 + kt * 32 + (l >> 4) * 8]);
      acc = __builtin_amdgcn_mfma_f32_16x16x32_bf16(a, warr[kt], acc, 0, 0, 0);
    }
#pragma unroll
    for (int r = 0; r < 4; ++r)
      gS[wb * 16 + (l >> 4) * 4 + r][wn * 16 + (l & 15)] = acc[r];
    __syncthreads();

    float zi = gS[eb][ec]      + b2f(x0);
    float zf = gS[eb][8 + ec]  + b2f(x1);
    float zg = gS[eb][16 + ec] + b2f(x2);
    float zo = gS[eb][24 + ec] + b2f(x3);
    float ig = sigmoidf_(zi), fg = sigmoidf_(zf), og = sigmoidf_(zo);
    float gg = tanh_fast(zg);
    c = fg * c + ig * gg;
    float hn = og * tanh_fast(c);
    int oidx = (eb << 19) + (t << 10) + col0 + ec;
    Hout[oidx] = hn;
    Cout[oidx] = c;
    hS[eb][ec] = f2b(hn);
    __syncthreads();

    if (t < 511) {
      unsigned short* hnx = hbuf + ((t + 1) & 1) * 65536;
      if (tid < 128) {
        int b = tid >> 1, sg = tid & 1;
        unsigned long long v = *reinterpret_cast<const unsigned long long*>(&hS[b][sg * 4]);
        __hip_atomic_store(reinterpret_cast<unsigned long long*>(hnx + b * 1024 + col0 + sg * 4),
                           v, __ATOMIC_RELAXED, __HIP_MEMORY_SCOPE_AGENT);
      }
      asm volatile("s_waitcnt vmcnt(0)" ::: "memory");   // all waves drain own stores
      __syncthreads();                                   // -> every store is at LLC
      if (tid == 0) {
        __hip_atomic_fetch_add(&cnt[t], 1, __ATOMIC_RELAXED, __HIP_MEMORY_SCOPE_AGENT);
        while (__hip_atomic_load(&cnt[t], __ATOMIC_RELAXED, __HIP_MEMORY_SCOPE_AGENT) < NBLK)
          __builtin_amdgcn_s_sleep(2);
      }
      __syncthreads();
    }
  }
}

extern "C" void kernel_launch(void* const* d_in, const int* in_sizes, int n_in,
                              void* d_out, int out_size, void* d_ws, size_t ws_size,
                              hipStream_t stream) {
  const float* x    = (const float*)d_in[0];
  const float* W_ih = (const float*)d_in[1];
  const float* W_hh = (const float*)d_in[2];
  const float* b_ih = (const float*)d_in[3];
  const float* b_hh = (const float*)d_in[4];

  char* ws = (char*)d_ws;
  int* cnt             = (int*)ws;                         // 4 KB counters
  unsigned short* hbuf = (unsigned short*)(ws + 4096);     // 2 x 64x1024 bf16 (256 KB)
  float* biasS         = (float*)(ws + 266240);            // 4096 f32
  unsigned short* Wihb = (unsigned short*)(ws + 282624);   // 8 MB bf16
  unsigned short* Whhb = (unsigned short*)(ws + 8671232);  // 8 MB bf16
  unsigned short* xgb  = (unsigned short*)(ws + 17059840); // 268 MB bf16 [32768][4096]
  float* out = (float*)d_out;

  (void)hipMemsetAsync(ws, 0, 266240, stream);             // zero counters + h0
  cvt_bf16_k<<<4096, 256, 0, stream>>>(W_ih, Wihb, 1048576);
  cvt_bf16_k<<<4096, 256, 0, stream>>>(W_hh, Whhb, 1048576);
  bias_k<<<16, 256, 0, stream>>>(b_ih, b_hh, biasS);
  gemm_xg_k<<<dim3(32, 256), 256, 0, stream>>>(x, Wihb, biasS, xgb);
  lstm_rec_k<<<NBLK, 512, 0, stream>>>(Whhb, xgb, hbuf, cnt, out);
}